// Round 9
// baseline (162.178 us; speedup 1.0000x reference)
//
#include <hip/hip_runtime.h>
#include <math.h>

#define Bn 16
#define Tn 2048
#define En 128
#define Hn 128

typedef _Float16 f16;
typedef _Float16 f16x8 __attribute__((ext_vector_type(8)));
typedef _Float16 f16x4 __attribute__((ext_vector_type(4)));
typedef float    f32x4 __attribute__((ext_vector_type(4)));

#define MFMA16(a, b, c) __builtin_amdgcn_mfma_f32_16x16x32_f16(a, b, c, 0, 0, 0)

// ---------------------------------------------------------------------------
// Kernel 0: Wt[p][n][k] = W_p[k][n] f16, via LDS transpose.  (R6, verified)
// ---------------------------------------------------------------------------
__global__ __launch_bounds__(256) void prep_wt(
    const float* __restrict__ Wq, const float* __restrict__ Wk,
    const float* __restrict__ Wv, f16* __restrict__ Wt)
{
    __shared__ f16 lds[En][Hn + 8];
    const int t = threadIdx.x;
    const int p = blockIdx.x;
    const float* W = (p == 0) ? Wq : (p == 1) ? Wk : Wv;

    #pragma unroll
    for (int i = 0; i < 16; ++i) {
        int idx = t + i * 256;
        int k = idx >> 5, n4 = idx & 31;
        float4 v = ((const float4*)W)[idx];
        #pragma unroll
        for (int j = 0; j < 4; ++j)
            lds[n4 * 4 + j][k] = (f16)(&v.x)[j];
    }
    __syncthreads();
    #pragma unroll
    for (int i = 0; i < 8; ++i) {
        int idx = t + i * 256;
        int n = idx >> 4, c = idx & 15;
        *(f16x8*)(Wt + p * En * Hn + n * Hn + c * 8) = *(const f16x8*)&lds[n][c * 8];
    }
}

// ---------------------------------------------------------------------------
// Kernel 1: Q/K/V projection — BARRIER-FREE wave-per-block version.
// 2048 blocks x 64 thr; each wave: 16 x-rows, all 384 out-cols.
// W^T read direct from global (96KB total, L1/L2-hot: shared by all waves).
// Outputs staged through wave-private LDS (in-wave lgkm ordering only,
// pattern HW-validated R3/R6) -> coalesced f16x8 stores.
// Q pre-scaled by (1/sqrt(H))*log2(e): attn softmax runs in exp2 domain.
// ---------------------------------------------------------------------------
__global__ __launch_bounds__(64, 2) void qkv_proj(
    const float* __restrict__ x, const f16* __restrict__ Wt,
    const float* __restrict__ bq, const float* __restrict__ bk,
    const float* __restrict__ bv,
    f16* __restrict__ Qo, f16* __restrict__ Ko, f16* __restrict__ Vtp)
{
    __shared__ f16 ot[16][En + 8];     // 4352 B : Q/K out tile [r][h]
    __shared__ f16 vb_[128][24];       // 6144 B : V^T out tile [h][r] (+8 pad)

    const int lane = threadIdx.x;
    const int ln = lane & 15, hi = lane >> 4;
    const long row0 = (long)blockIdx.x * 16;
    const int b  = (int)(row0 >> 11);
    const int t0 = (int)(row0 & 2047);

    // A-fragments: lane ln owns x row (row0+ln); fp32 -> f16 in regs
    f16x8 xf[4];
    {
        const float* xr = x + (row0 + ln) * En;
        #pragma unroll
        for (int kss = 0; kss < 4; ++kss) {
            float4 a = *(const float4*)(xr + kss * 32 + hi * 8);
            float4 c = *(const float4*)(xr + kss * 32 + hi * 8 + 4);
            f16x8 h = { (f16)a.x, (f16)a.y, (f16)a.z, (f16)a.w,
                        (f16)c.x, (f16)c.y, (f16)c.z, (f16)c.w };
            xf[kss] = h;
        }
    }

    const float* bias[3] = { bq, bk, bv };

    #pragma unroll
    for (int p = 0; p < 3; ++p) {
        f32x4 acc[8];
        #pragma unroll
        for (int i = 0; i < 8; ++i) acc[i] = (f32x4){0.f, 0.f, 0.f, 0.f};

        #pragma unroll
        for (int kss = 0; kss < 4; ++kss) {
            f16x8 wf[8];
            #pragma unroll
            for (int nt = 0; nt < 8; ++nt)
                wf[nt] = *(const f16x8*)(Wt + ((long)(p * Hn + nt * 16 + ln)) * En
                                         + kss * 32 + hi * 8);
            #pragma unroll
            for (int nt = 0; nt < 8; ++nt)
                acc[nt] = MFMA16(xf[kss], wf[nt], acc[nt]);
        }

        if (p < 2) {
            const float scl = (p == 0)
                ? 0.08838834764831845f * 1.4426950408889634f : 1.0f;
            #pragma unroll
            for (int nt = 0; nt < 8; ++nt) {
                int col = nt * 16 + ln;
                float bvv = bias[p][col];
                #pragma unroll
                for (int reg = 0; reg < 4; ++reg)
                    ot[hi * 4 + reg][col] = (f16)((acc[nt][reg] + bvv) * scl);
            }
            f16* dst = (p == 0) ? Qo : Ko;      // in-wave lgkm orders ot
            #pragma unroll
            for (int i = 0; i < 4; ++i) {
                int idx = lane + i * 64;        // 256 chunks: 16 rows x 16
                int r = idx >> 4, c = idx & 15;
                *(f16x8*)(dst + (row0 + r) * Hn + c * 8) = *(const f16x8*)&ot[r][c * 8];
            }
        } else {
            #pragma unroll
            for (int nt = 0; nt < 8; ++nt) {
                int col = nt * 16 + ln;
                float bvv = bias[2][col];
                f16x4 hv;
                #pragma unroll
                for (int reg = 0; reg < 4; ++reg)
                    hv[reg] = (f16)(acc[nt][reg] + bvv);
                *(f16x4*)&vb_[col][hi * 4] = hv;
            }
            #pragma unroll
            for (int i = 0; i < 4; ++i) {
                int idx = lane + i * 64;        // 256 chunks: 128 rows x 2
                int h = idx >> 1, c = idx & 1;
                *(f16x8*)(Vtp + ((long)b * Hn + h) * Tn + t0 + c * 8) =
                    *(const f16x8*)&vb_[h][c * 8];
            }
        }
    }
}

// ---------------------------------------------------------------------------
// Kernel 2: causal flash attention, f16 MFMA, fp32 accum, exp2-domain.
// SPLIT-KV: QB=32, 4 waves; waves 0,1 (stream E) process even KB-32 tiles,
// waves 2,3 (stream O) odd tiles, of the same 32 q-rows.  4096 waves total
// = 16/CU nominal (LDS 43008B -> 3 blocks/CU resident).  Streams combine
// at the end via LDS exchange (flash merge).  Defer-max, lane-partial l,
// wave-private psh, T14 reg-prefetch, dispatch-order LPT (qi descending).
// ---------------------------------------------------------------------------
__global__ __launch_bounds__(256, 3) void attn_fwd(
    const f16* __restrict__ Qf, const f16* __restrict__ Kf,
    const f16* __restrict__ Vt, float* __restrict__ Out)
{
    __shared__ __align__(16) unsigned char smem[43008];
    f16 (*kshE)[136] = (f16 (*)[136])(smem);            //  8704 B [32][136]
    f16 (*kshO)[136] = (f16 (*)[136])(smem + 8704);     //  8704 B
    f16 (*vshE)[40]  = (f16 (*)[40])(smem + 17408);     // 10240 B [128][40]
    f16 (*vshO)[40]  = (f16 (*)[40])(smem + 27648);     // 10240 B
    f16 (*psh)[40]   = (f16 (*)[40])(smem + 37888);     //  5120 B [64][40]
    float (*xch)[41] = (float (*)[41])(smem);           // 20992 B alias (epilogue)

    const int t = threadIdx.x;
    const int w = t >> 6, lane = t & 63;
    const int ln = lane & 15, hi = lane >> 4;
    const int st = w >> 1;            // 0: even tiles, 1: odd tiles
    const int wr = w & 1;             // row half: rows 16*wr..16*wr+15

    const int n = blockIdx.x;
    const int bb = n & 15;
    const int qi = 63 - (n >> 4);     // descending work for tail packing
    const int q0 = qi * 32;
    const int nsteps = (qi >> 1) + 1; // tiles 0..qi split into E/O streams
    const long qbase = ((long)bb * Tn + q0) * Hn;
    const f16* __restrict__ Kg = Kf + (long)bb * Tn * Hn;
    const f16* __restrict__ Vg = Vt + (long)bb * Hn * Tn;

    f16 (*ksh)[136] = st ? kshO : kshE;
    f16 (*vsh)[40]  = st ? vshO : vshE;

    // Q fragments: wave's 16 rows = q0 + 16*wr + ln
    f16x8 qfr[4];
    #pragma unroll
    for (int kss = 0; kss < 4; ++kss)
        qfr[kss] = *(const f16x8*)(Qf + qbase + (long)(16 * wr + ln) * Hn
                                   + kss * 32 + hi * 8);

    f32x4 oacc[8];
    #pragma unroll
    for (int i = 0; i < 8; ++i) oacc[i] = (f32x4){0.f, 0.f, 0.f, 0.f};
    float mrow[4], lpart[4];
    #pragma unroll
    for (int i = 0; i < 4; ++i) { mrow[i] = -INFINITY; lpart[i] = 0.f; }

    // ---- prologue: stage tiles 0 (E) and 1 (O); tile 1 may be unused ----
    #pragma unroll
    for (int i = 0; i < 2; ++i) {
        int idx = t + i * 256;
        int kr = idx >> 4, kc = idx & 15;          // K: 32 rows x 16 chunks
        int vr = idx >> 2, vc = idx & 3;           // V: 128 rows x 4 chunks
        *(f16x8*)&kshE[kr][kc * 8] = *(const f16x8*)(Kg + (long)kr * Hn + kc * 8);
        *(f16x8*)&kshO[kr][kc * 8] = *(const f16x8*)(Kg + (long)(32 + kr) * Hn + kc * 8);
        *(f16x8*)&vshE[vr][vc * 8] = *(const f16x8*)(Vg + (long)vr * Tn + vc * 8);
        *(f16x8*)&vshO[vr][vc * 8] = *(const f16x8*)(Vg + (long)vr * Tn + 32 + vc * 8);
    }
    __syncthreads();

    for (int s = 0; s < nsteps; ++s) {
        const bool pre = (s + 1 < nsteps);

        // T14 prefetch: next step's E and O tiles into registers
        f16x8 pkE[2], pkO[2], pvE[2], pvO[2];
        if (pre) {
            const int kE = (2 * (s + 1)) * 32, kO = kE + 32;
            #pragma unroll
            for (int i = 0; i < 2; ++i) {
                int idx = t + i * 256;
                int kr = idx >> 4, kc = idx & 15;
                int vr = idx >> 2, vc = idx & 3;
                pkE[i] = *(const f16x8*)(Kg + (long)(kE + kr) * Hn + kc * 8);
                pkO[i] = *(const f16x8*)(Kg + (long)(kO + kr) * Hn + kc * 8);
                pvE[i] = *(const f16x8*)(Vg + (long)vr * Tn + kE + vc * 8);
                pvO[i] = *(const f16x8*)(Vg + (long)vr * Tn + kO + vc * 8);
            }
        }

        const int myT = 2 * s + st;
        if (myT <= qi) {
            const int k0 = myT * 32;
            // ---- QK^T: 16 q-rows x 32 keys ----
            f32x4 sacc[2];
            sacc[0] = (f32x4){0.f, 0.f, 0.f, 0.f};
            sacc[1] = (f32x4){0.f, 0.f, 0.f, 0.f};
            __builtin_amdgcn_s_setprio(1);
            #pragma unroll
            for (int kss = 0; kss < 4; ++kss) {
                #pragma unroll
                for (int nt = 0; nt < 2; ++nt) {
                    f16x8 bf = *(const f16x8*)&ksh[nt * 16 + ln][kss * 32 + hi * 8];
                    sacc[nt] = MFMA16(qfr[kss], bf, sacc[nt]);
                }
            }
            __builtin_amdgcn_s_setprio(0);

            // ---- mask (diagonal tile only) ----
            const bool diag = (myT == qi);
            float sv[4][2];
            #pragma unroll
            for (int reg = 0; reg < 4; ++reg) {
                int gq = q0 + 16 * wr + hi * 4 + reg;
                #pragma unroll
                for (int nt = 0; nt < 2; ++nt) {
                    float v = sacc[nt][reg];
                    if (diag) v = (k0 + nt * 16 + ln <= gq) ? v : -1e12f;
                    sv[reg][nt] = v;
                }
            }

            // ---- defer-max trigger (lane-local) ----
            float worst = -INFINITY;
            #pragma unroll
            for (int reg = 0; reg < 4; ++reg)
                worst = fmaxf(worst, fmaxf(sv[reg][0], sv[reg][1]) - mrow[reg]);
            if (__any(worst > 11.5415603f)) {    // 8 nats, ~once per stream
                #pragma unroll
                for (int reg = 0; reg < 4; ++reg) {
                    float mx = fmaxf(sv[reg][0], sv[reg][1]);
                    mx = fmaxf(mx, __shfl_xor(mx, 1));
                    mx = fmaxf(mx, __shfl_xor(mx, 2));
                    mx = fmaxf(mx, __shfl_xor(mx, 4));
                    mx = fmaxf(mx, __shfl_xor(mx, 8));
                    float mnew = fmaxf(mrow[reg], mx);
                    float f = exp2f(mrow[reg] - mnew);
                    mrow[reg] = mnew;
                    lpart[reg] *= f;
                    #pragma unroll
                    for (int nt2 = 0; nt2 < 8; ++nt2) oacc[nt2][reg] *= f;
                }
            }

            // ---- P = 2^(s-m), lane-partial l, stash in wave-private psh ----
            #pragma unroll
            for (int reg = 0; reg < 4; ++reg) {
                float p0 = exp2f(sv[reg][0] - mrow[reg]);
                float p1 = exp2f(sv[reg][1] - mrow[reg]);
                lpart[reg] += p0 + p1;
                int qr = w * 16 + hi * 4 + reg;
                psh[qr][ln]      = (f16)p0;
                psh[qr][ln + 16] = (f16)p1;
            }

            // ---- PV: P(16x32) x V^T ----
            __builtin_amdgcn_s_setprio(1);
            {
                f16x8 pa = *(const f16x8*)&psh[w * 16 + ln][hi * 8];
                #pragma unroll
                for (int nt = 0; nt < 8; ++nt) {
                    f16x8 vb = *(const f16x8*)&vsh[nt * 16 + ln][hi * 8];
                    oacc[nt] = MFMA16(pa, vb, oacc[nt]);
                }
            }
            __builtin_amdgcn_s_setprio(0);
        }

        __syncthreads();                 // all waves done with ksh/vsh
        if (pre) {
            #pragma unroll
            for (int i = 0; i < 2; ++i) {
                int idx = t + i * 256;
                int kr = idx >> 4, kc = idx & 15;
                int vr = idx >> 2, vc = idx & 3;
                *(f16x8*)&kshE[kr][kc * 8] = pkE[i];
                *(f16x8*)&kshO[kr][kc * 8] = pkO[i];
                *(f16x8*)&vshE[vr][vc * 8] = pvE[i];
                *(f16x8*)&vshO[vr][vc * 8] = pvO[i];
            }
            __syncthreads();
        }
    }

    // ---- stream combine: O-waves export; E-waves merge + store ----
    if (st == 1) {
        float* xr = xch[wr * 64 + lane];
        #pragma unroll
        for (int nt = 0; nt < 8; ++nt)
            #pragma unroll
            for (int reg = 0; reg < 4; ++reg)
                xr[nt * 4 + reg] = oacc[nt][reg];
        #pragma unroll
        for (int reg = 0; reg < 4; ++reg) {
            xr[32 + reg] = mrow[reg];
            xr[36 + reg] = lpart[reg];
        }
    }
    __syncthreads();
    if (st == 0) {
        const float* xr = xch[wr * 64 + lane];   // partner wave w+2 (same rows)
        #pragma unroll
        for (int reg = 0; reg < 4; ++reg) {
            float mO = xr[32 + reg], lO = xr[36 + reg];
            float m  = fmaxf(mrow[reg], mO);
            float fE = exp2f(mrow[reg] - m);     // mrow finite (tile 0 in E)
            float fO = exp2f(mO - m);            // mO may be -inf -> fO = 0
            float lr = lpart[reg] * fE + lO * fO;
            lr += __shfl_xor(lr, 1);
            lr += __shfl_xor(lr, 2);
            lr += __shfl_xor(lr, 4);
            lr += __shfl_xor(lr, 8);
            float inv = 1.0f / lr;
            long orow = qbase + (long)(16 * wr + hi * 4 + reg) * Hn;
            #pragma unroll
            for (int nt = 0; nt < 8; ++nt)
                Out[orow + nt * 16 + ln] =
                    (oacc[nt][reg] * fE + xr[nt * 4 + reg] * fO) * inv;
        }
    }
}

// ---------------------------------------------------------------------------
extern "C" void kernel_launch(void* const* d_in, const int* in_sizes, int n_in,
                              void* d_out, int out_size, void* d_ws, size_t ws_size,
                              hipStream_t stream)
{
    const float* x  = (const float*)d_in[0];
    const float* Wq = (const float*)d_in[1];
    const float* bq = (const float*)d_in[2];
    const float* Wk = (const float*)d_in[3];
    const float* bk = (const float*)d_in[4];
    const float* Wv = (const float*)d_in[5];
    const float* bv = (const float*)d_in[6];

    // Workspace (f16): Q | K | V^T | Wt  — ~25.3 MB
    const size_t NE = (size_t)Bn * Tn * Hn;   // 4,194,304
    f16* Qf = (f16*)d_ws;
    f16* Kf = Qf + NE;
    f16* Vt = Kf + NE;
    f16* Wt = Vt + NE;

    prep_wt<<<dim3(3), dim3(256), 0, stream>>>(Wq, Wk, Wv, Wt);
    qkv_proj<<<dim3((Bn * Tn) / 16), dim3(64), 0, stream>>>(
        x, Wt, bq, bk, bv, Qf, Kf, Vt);
    attn_fwd<<<dim3(1024), dim3(256), 0, stream>>>(Qf, Kf, Vt, (float*)d_out);
}